// Round 1
// baseline (177.599 us; speedup 1.0000x reference)
//
#include <hip/hip_runtime.h>
#include <math.h>

#define NW 14
#define NSTATE 16384           // 2^14 amplitudes
#define NL 4
#define BATCH 128
#define TPB 1024
#define APT (NSTATE / TPB)     // 16 amplitudes per thread
#define PPT (NSTATE / 2 / TPB) // 8 gate-pairs per thread

// Composite of the per-layer CNOT ring CNOT(0,1)..CNOT(12,13),CNOT(13,0) as a
// single GF(2)-linear read-index map: psi_new[idx] = psi_old[R(idx)].
// Wire i lives at bit position (13-i). Derivation (verified vs sequential
// application): positions 0..11: r_p = b_p ^ b_{p+1}; pos13 = b13^b0;
// pos12 = b12^b13^b0.
__device__ __forceinline__ unsigned perm_read_idx(unsigned idx) {
    unsigned u = (idx ^ (idx >> 1)) & 0x0FFFu;
    unsigned p13 = ((idx >> 13) ^ idx) & 1u;
    unsigned p12 = ((idx >> 12) & 1u) ^ p13;
    return u | (p12 << 12) | (p13 << 13);
}

__global__ __launch_bounds__(TPB) void qsim_kernel(
    const float* __restrict__ states,
    const float* __restrict__ weights,
    const float* __restrict__ head_w,
    const float* __restrict__ head_b,
    float* __restrict__ out)
{
    extern __shared__ float2 psi[];  // 16384 float2 = 128 KB (one block/CU)
    const int b = blockIdx.x;
    const int tid = threadIdx.x;

    // |0...0>
    for (int t = tid; t < NSTATE; t += TPB)
        psi[t] = make_float2(t == 0 ? 1.0f : 0.0f, 0.0f);
    __syncthreads();

    for (int l = 0; l < NL; ++l) {
        for (int w = 0; w < NW; ++w) {
            // Fused gate G = RZ(t2) * RX(t1); layer 0 additionally folds the
            // data-encoding RX(|states[b,w]|) in (RX angles add).
            float t1 = weights[(l * NW + w) * 2 + 0];
            float t2 = weights[(l * NW + w) * 2 + 1];
            if (l == 0) t1 += fabsf(states[(size_t)b * NSTATE + w]);
            float s, c, sz, cz;
            sincosf(0.5f * t1, &s, &c);
            sincosf(0.5f * t2, &sz, &cz);
            // g00=(c*cz,-c*sz) g01=(-s*sz,-s*cz) g10=(s*sz,-s*cz) g11=(c*cz,c*sz)
            const float g00r =  c * cz, g00i = -c * sz;
            const float g01r = -s * sz, g01i = -s * cz;
            const float g10r =  s * sz, g10i = -s * cz;
            const float g11r =  c * cz, g11i =  c * sz;

            const int bw = 13 - w;          // bit position of wire w
            const unsigned stride = 1u << bw;
#pragma unroll
            for (int t = 0; t < PPT; ++t) {
                unsigned p  = (unsigned)tid + (unsigned)t * TPB;
                unsigned i0 = ((p >> bw) << (bw + 1)) | (p & (stride - 1u));
                unsigned i1 = i0 | stride;
                float2 a0 = psi[i0];
                float2 a1 = psi[i1];
                float2 n0, n1;
                n0.x = g00r * a0.x - g00i * a0.y + g01r * a1.x - g01i * a1.y;
                n0.y = g00r * a0.y + g00i * a0.x + g01r * a1.y + g01i * a1.x;
                n1.x = g10r * a0.x - g10i * a0.y + g11r * a1.x - g11i * a1.y;
                n1.y = g10r * a0.y + g10i * a0.x + g11r * a1.y + g11i * a1.x;
                psi[i0] = n0;
                psi[i1] = n1;
            }
            __syncthreads();
        }

        // CNOT ring as one in-place permutation: gather to regs, barrier, scatter.
        float2 v[APT];
#pragma unroll
        for (int t = 0; t < APT; ++t) {
            unsigned idx = (unsigned)tid + (unsigned)t * TPB;
            v[t] = psi[perm_read_idx(idx)];
        }
        __syncthreads();
#pragma unroll
        for (int t = 0; t < APT; ++t)
            psi[(unsigned)tid + (unsigned)t * TPB] = v[t];
        __syncthreads();
    }

    // out[b] = sum_idx |psi|^2 * (sum_i head_w[i]*(1-2*bit_i)) + head_b
    float hw[NW];
#pragma unroll
    for (int i = 0; i < NW; ++i) hw[i] = head_w[i];

    float acc = 0.0f;
#pragma unroll
    for (int t = 0; t < APT; ++t) {
        unsigned idx = (unsigned)tid + (unsigned)t * TPB;
        float2 a = psi[idx];
        float p = a.x * a.x + a.y * a.y;
        float cv = 0.0f;
#pragma unroll
        for (int i = 0; i < NW; ++i)
            cv += ((idx >> (13 - i)) & 1u) ? -hw[i] : hw[i];
        acc += p * cv;
    }
    // wave(64) reduce, then cross-wave via LDS
#pragma unroll
    for (int off = 32; off > 0; off >>= 1)
        acc += __shfl_down(acc, off, 64);
    __shared__ float wsum[TPB / 64];
    if ((tid & 63) == 0) wsum[tid >> 6] = acc;
    __syncthreads();
    if (tid == 0) {
        float tot = 0.0f;
#pragma unroll
        for (int i = 0; i < TPB / 64; ++i) tot += wsum[i];
        out[b] = tot + head_b[0];
    }
}

extern "C" void kernel_launch(void* const* d_in, const int* in_sizes, int n_in,
                              void* d_out, int out_size, void* d_ws, size_t ws_size,
                              hipStream_t stream) {
    const float* states = (const float*)d_in[0];   // (128, 16384)
    const float* weights = (const float*)d_in[1];  // (4, 14, 2)
    const float* head_w = (const float*)d_in[2];   // (1, 14)
    const float* head_b = (const float*)d_in[3];   // (1,)
    float* out = (float*)d_out;                    // (128,)
    qsim_kernel<<<BATCH, TPB, NSTATE * sizeof(float2), stream>>>(
        states, weights, head_w, head_b, out);
}

// Round 3
// 173.890 us; speedup vs baseline: 1.0213x; 1.0213x over previous
//
#include <hip/hip_runtime.h>
#include <math.h>

#define NW 14
#define NSTATE 16384           // 2^14 amplitudes
#define NL 4
#define BATCH 128
#define TPB 1024

// ---------------------------------------------------------------------------
// Index convention (round-1 PASSING kernel): wire i lives at bit (13-i).
//
// CNOT-ring composite: psi_new[idx] = psi_old[R(idx)],
//   R: y_p = x_p ^ x_{p+1} (p=0..11), y_12 = x12^x13^x0, y_13 = x13^x0.
// Scatter form: value at I goes to R^{-1}(I). GF(2)-linear basis images
// (each verified by applying R): R^{-1}(e_j) = ((2<<j)-1) | (1<<13) (j<=11),
// R^{-1}(e_12) = 0x3FFF, R^{-1}(e_13) = 0x1FFF.
// ---------------------------------------------------------------------------

#define B4_  0x201Fu
#define B5_  0x203Fu
#define B12_ 0x3FFFu
#define B13_ 0x1FFFu

// Apply SU(2) gate [[a,b],[-b*,a*]] (g={ar,ai,br,bi}) on register pairs
// (k, k|M). Register k holds the amplitude whose index-bit equals
// (swizzle s)-bit for that position, so when the s-bit is set the pair
// orientation is swapped: apply X*G*X = [[a*,-b*],[b,a]] instead, which in
// this packing is just (ai,br) -> (-ai,-br).
template<int M>
__device__ __forceinline__ void gate16(float2* r, float4 g, unsigned s) {
    const float f = (s & (unsigned)M) ? -1.0f : 1.0f;
    g.y *= f;   // ai
    g.z *= f;   // br
#pragma unroll
    for (int k = 0; k < 16; ++k) {
        if ((k & M) == 0) {
            const float x0 = r[k].x,   y0 = r[k].y;
            const float x1 = r[k|M].x, y1 = r[k|M].y;
            r[k].x   =  g.x*x0 - g.y*y0 + g.z*x1 - g.w*y1;
            r[k].y   =  g.x*y0 + g.y*x0 + g.z*y1 + g.w*x1;
            r[k|M].x = -g.z*x0 - g.w*y0 + g.x*x1 + g.y*y1;
            r[k|M].y = -g.z*y0 + g.w*x0 + g.x*y1 - g.y*x1;
        }
    }
}

// One pass: gather 16 amps varying in index bits [J0, J0+3], apply those 4
// gates in registers, scatter back. XOR swizzle (k^s) spreads bank pairs
// (4-way max aliasing instead of 32-way); orientation handled in gate16.
template<int J0>
__device__ __forceinline__ void pass4gates(float2* psi, const float4* gc4,
                                           int l, unsigned t) {
    const unsigned s = t & 15u;
    const unsigned low  = t & ((1u << J0) - 1u);
    const unsigned high = (t >> J0) << (J0 + 4);
    float2 r[16];
#pragma unroll
    for (int k = 0; k < 16; ++k)
        r[k] = psi[low | ((unsigned)(k ^ (int)s) << J0) | high];
    gate16<1>(r, gc4[l*NW + (13 - (J0+0))], s);
    gate16<2>(r, gc4[l*NW + (13 - (J0+1))], s);
    gate16<4>(r, gc4[l*NW + (13 - (J0+2))], s);
    gate16<8>(r, gc4[l*NW + (13 - (J0+3))], s);
#pragma unroll
    for (int k = 0; k < 16; ++k)
        psi[low | ((unsigned)(k ^ (int)s) << J0) | high] = r[k];
}

// Last pass of a layer: gates on bits 12,13 (wires 1,0) + CNOT-ring
// permutation folded into the scatter. Thread owns index bits {0..3}<-t&15,
// {4,5}<-u&3, {6..11}<-t>>4, {12,13}<-u>>2 where u=k^s.
__device__ __forceinline__ void pass_last(float2* psi, const float4* gc4,
                                          int l, unsigned t) {
    const unsigned s = t & 15u;
    const unsigned base = (t & 15u) | ((t >> 4) << 6);
    float2 r[16];
#pragma unroll
    for (int k = 0; k < 16; ++k) {
        const unsigned u = (unsigned)(k ^ (int)s) & 15u;
        r[k] = psi[base | ((u & 3u) << 4) | ((u >> 2) << 12)];
    }
    gate16<4>(r, gc4[l*NW + 1], s);   // index bit 12 -> wire 1
    gate16<8>(r, gc4[l*NW + 0], s);   // index bit 13 -> wire 0
    __syncthreads();               // in-place permutation: drain all gathers
    // R^{-1}(base) via suffix-XOR (base has bits only in 0..11):
    // low-12 = suffix-xor, bit13 = popcount parity, bit12 = 0.
    unsigned v = base;
    v ^= v >> 1; v ^= v >> 2; v ^= v >> 4; v ^= v >> 8;
    const unsigned Rbase = (v & 0x0FFFu) | ((v & 1u) << 13);
    const unsigned Rs = ((s & 1u) ? B4_  : 0u) ^ ((s & 2u) ? B5_  : 0u) ^
                        ((s & 4u) ? B12_ : 0u) ^ ((s & 8u) ? B13_ : 0u);
    const unsigned Rb = Rbase ^ Rs;
#pragma unroll
    for (int k = 0; k < 16; ++k) {
        const unsigned CK = ((k & 1) ? B4_  : 0u) ^ ((k & 2) ? B5_  : 0u) ^
                            ((k & 4) ? B12_ : 0u) ^ ((k & 8) ? B13_ : 0u);
        psi[Rb ^ CK] = r[k];
    }
}

__global__ __launch_bounds__(TPB) void qsim_kernel(
    const float* __restrict__ states,
    const float* __restrict__ weights,
    const float* __restrict__ head_w,
    const float* __restrict__ head_b,
    float* __restrict__ out)
{
    extern __shared__ float2 psi[];        // 16384 float2 = 128 KB
    __shared__ float4 gc4[NL * NW];        // fused gate coefs (a, b)
    __shared__ float wsum[TPB / 64];

    const int b = blockIdx.x;
    const unsigned tid = threadIdx.x;

    // One-time gate-coef precompute: G = RZ(t2)*RX(t1), layer 0 folds the
    // data-encoding RX(|x_w|) in (RX angles add). SU(2): a=g00, b=g01.
    if (tid < NL * NW) {
        const int l = (int)tid / NW, w = (int)tid % NW;
        float t1 = weights[tid * 2 + 0];
        float t2 = weights[tid * 2 + 1];
        if (l == 0) t1 += fabsf(states[(size_t)b * NSTATE + w]);
        float s, c, sz, cz;
        sincosf(0.5f * t1, &s, &c);
        sincosf(0.5f * t2, &sz, &cz);
        gc4[tid] = make_float4(c * cz, -c * sz, -s * sz, -s * cz);
    }
    // |0...0>
    for (unsigned i = tid; i < NSTATE; i += TPB)
        psi[i] = make_float2(i == 0 ? 1.0f : 0.0f, 0.0f);
    __syncthreads();

    for (int l = 0; l < NL; ++l) {
        pass4gates<0>(psi, gc4, l, tid);  __syncthreads();  // wires 13..10
        pass4gates<4>(psi, gc4, l, tid);  __syncthreads();  // wires 9..6
        pass4gates<8>(psi, gc4, l, tid);  __syncthreads();  // wires 5..2
        pass_last    (psi, gc4, l, tid);  __syncthreads();  // wires 1,0 + ring
    }

    // out[b] = sum |amp|^2 * cv(idx) + head_b ; cv = sum_i hw[i]*(1-2*bit)
    float hw[NW];
#pragma unroll
    for (int i = 0; i < NW; ++i) hw[i] = head_w[i];

    const unsigned s = tid & 15u;
    // cvbase for index bits 4..13 (= bits 0..9 of tid); bit j <-> wire 13-j
    float cvbase = 0.0f;
#pragma unroll
    for (int i = 0; i < NW; ++i) cvbase += hw[i];
#pragma unroll
    for (int j = 4; j < 14; ++j)
        if ((tid >> (j - 4)) & 1u) cvbase -= 2.0f * hw[13 - j];

    float acc = 0.0f;
#pragma unroll
    for (int k = 0; k < 16; ++k) {
        const unsigned u = (unsigned)(k ^ (int)s) & 15u;   // index bits 0..3
        const float2 a = psi[u | (tid << 4)];
        const float p = a.x * a.x + a.y * a.y;
        float cv = cvbase;
        if (u & 1u) cv -= 2.0f * hw[13];
        if (u & 2u) cv -= 2.0f * hw[12];
        if (u & 4u) cv -= 2.0f * hw[11];
        if (u & 8u) cv -= 2.0f * hw[10];
        acc += p * cv;
    }
#pragma unroll
    for (int off = 32; off > 0; off >>= 1)
        acc += __shfl_down(acc, off, 64);
    if ((tid & 63u) == 0) wsum[tid >> 6] = acc;
    __syncthreads();
    if (tid == 0) {
        float tot = 0.0f;
#pragma unroll
        for (int i = 0; i < TPB / 64; ++i) tot += wsum[i];
        out[b] = tot + head_b[0];
    }
}

extern "C" void kernel_launch(void* const* d_in, const int* in_sizes, int n_in,
                              void* d_out, int out_size, void* d_ws, size_t ws_size,
                              hipStream_t stream) {
    const float* states  = (const float*)d_in[0];  // (128, 16384)
    const float* weights = (const float*)d_in[1];  // (4, 14, 2)
    const float* head_w  = (const float*)d_in[2];  // (1, 14)
    const float* head_b  = (const float*)d_in[3];  // (1,)
    float* out = (float*)d_out;                    // (128,)
    qsim_kernel<<<BATCH, TPB, NSTATE * sizeof(float2), stream>>>(
        states, weights, head_w, head_b, out);
}

// Round 4
// 173.760 us; speedup vs baseline: 1.0221x; 1.0007x over previous
//
#include <hip/hip_runtime.h>
#include <math.h>

#define NW 14
#define NSTATE 16384           // 2^14 amplitudes
#define NL 4
#define BATCH 128
#define TPB 1024

// ---------------------------------------------------------------------------
// Index convention (round-1 PASSING kernel): wire i lives at bit (13-i).
//
// CNOT-ring composite: psi_new[idx] = psi_old[R(idx)],
//   R: y_p = x_p ^ x_{p+1} (p=0..11), y_12 = x12^x13^x0, y_13 = x13^x0.
// Scatter form: value at I goes to R^{-1}(I). GF(2)-linear basis images
// (each verified by applying R): R^{-1}(e_j) = ((2<<j)-1) | (1<<13) (j<=11),
// R^{-1}(e_12) = 0x3FFF, R^{-1}(e_13) = 0x1FFF.
// ---------------------------------------------------------------------------

#define B4_  0x201Fu
#define B5_  0x203Fu
#define B12_ 0x3FFFu
#define B13_ 0x1FFFu

// Apply SU(2) gate [[a,b],[-b*,a*]] (g={ar,ai,br,bi}) on register pairs
// (k, k|M). Register k holds the amplitude whose index-bit equals
// (swizzle s)-bit for that position, so when the s-bit is set the pair
// orientation is swapped: apply X*G*X = [[a*,-b*],[b,a]] instead, which in
// this packing is just (ai,br) -> (-ai,-br).
template<int M>
__device__ __forceinline__ void gate16(float2* r, float4 g, unsigned s) {
    const float f = (s & (unsigned)M) ? -1.0f : 1.0f;
    g.y *= f;   // ai
    g.z *= f;   // br
#pragma unroll
    for (int k = 0; k < 16; ++k) {
        if ((k & M) == 0) {
            const float x0 = r[k].x,   y0 = r[k].y;
            const float x1 = r[k|M].x, y1 = r[k|M].y;
            r[k].x   =  g.x*x0 - g.y*y0 + g.z*x1 - g.w*y1;
            r[k].y   =  g.x*y0 + g.y*x0 + g.z*y1 + g.w*x1;
            r[k|M].x = -g.z*x0 - g.w*y0 + g.x*x1 + g.y*y1;
            r[k|M].y = -g.z*y0 + g.w*x0 + g.x*y1 - g.y*x1;
        }
    }
}

// One pass: gather 16 amps varying in index bits [J0, J0+3], apply those 4
// gates in registers, scatter back. XOR swizzle (k^s) spreads bank pairs
// (4-way max aliasing instead of 32-way); orientation handled in gate16.
template<int J0>
__device__ __forceinline__ void pass4gates(float2* psi, const float4* gc4,
                                           int l, unsigned t) {
    const unsigned s = t & 15u;
    const unsigned low  = t & ((1u << J0) - 1u);
    const unsigned high = (t >> J0) << (J0 + 4);
    float2 r[16];
#pragma unroll
    for (int k = 0; k < 16; ++k)
        r[k] = psi[low | ((unsigned)(k ^ (int)s) << J0) | high];
    gate16<1>(r, gc4[l*NW + (13 - (J0+0))], s);
    gate16<2>(r, gc4[l*NW + (13 - (J0+1))], s);
    gate16<4>(r, gc4[l*NW + (13 - (J0+2))], s);
    gate16<8>(r, gc4[l*NW + (13 - (J0+3))], s);
#pragma unroll
    for (int k = 0; k < 16; ++k)
        psi[low | ((unsigned)(k ^ (int)s) << J0) | high] = r[k];
}

// Last pass of a layer: gates on bits 12,13 (wires 1,0) + CNOT-ring
// permutation folded into the scatter. Thread owns index bits {0..3}<-t&15,
// {4,5}<-u&3, {6..11}<-t>>4, {12,13}<-u>>2 where u=k^s.
__device__ __forceinline__ void pass_last(float2* psi, const float4* gc4,
                                          int l, unsigned t) {
    const unsigned s = t & 15u;
    const unsigned base = (t & 15u) | ((t >> 4) << 6);
    float2 r[16];
#pragma unroll
    for (int k = 0; k < 16; ++k) {
        const unsigned u = (unsigned)(k ^ (int)s) & 15u;
        r[k] = psi[base | ((u & 3u) << 4) | ((u >> 2) << 12)];
    }
    gate16<4>(r, gc4[l*NW + 1], s);   // index bit 12 -> wire 1
    gate16<8>(r, gc4[l*NW + 0], s);   // index bit 13 -> wire 0
    __syncthreads();               // in-place permutation: drain all gathers
    // R^{-1}(base) via suffix-XOR (base has bits only in 0..11):
    // low-12 = suffix-xor, bit13 = popcount parity, bit12 = 0.
    unsigned v = base;
    v ^= v >> 1; v ^= v >> 2; v ^= v >> 4; v ^= v >> 8;
    const unsigned Rbase = (v & 0x0FFFu) | ((v & 1u) << 13);
    const unsigned Rs = ((s & 1u) ? B4_  : 0u) ^ ((s & 2u) ? B5_  : 0u) ^
                        ((s & 4u) ? B12_ : 0u) ^ ((s & 8u) ? B13_ : 0u);
    const unsigned Rb = Rbase ^ Rs;
#pragma unroll
    for (int k = 0; k < 16; ++k) {
        const unsigned CK = ((k & 1) ? B4_  : 0u) ^ ((k & 2) ? B5_  : 0u) ^
                            ((k & 4) ? B12_ : 0u) ^ ((k & 8) ? B13_ : 0u);
        psi[Rb ^ CK] = r[k];
    }
}

// __launch_bounds__(1024, 4): 4 waves/EU == the 1 block/CU the 128 KB LDS
// forces anyway. This raises the VGPR cap 64 -> 128 so the 32-VGPR r[16]
// working set stays in registers. Round 3 (no 2nd arg) capped at 64 VGPRs
// and spilled r[] to scratch: 114 MB HBM/dispatch, kernel scratch-BW-bound.
__global__ __launch_bounds__(TPB, 4) void qsim_kernel(
    const float* __restrict__ states,
    const float* __restrict__ weights,
    const float* __restrict__ head_w,
    const float* __restrict__ head_b,
    float* __restrict__ out)
{
    extern __shared__ float2 psi[];        // 16384 float2 = 128 KB
    __shared__ float4 gc4[NL * NW];        // fused gate coefs (a, b)
    __shared__ float wsum[TPB / 64];

    const int b = blockIdx.x;
    const unsigned tid = threadIdx.x;

    // One-time gate-coef precompute: G = RZ(t2)*RX(t1), layer 0 folds the
    // data-encoding RX(|x_w|) in (RX angles add). SU(2): a=g00, b=g01.
    if (tid < NL * NW) {
        const int l = (int)tid / NW, w = (int)tid % NW;
        float t1 = weights[tid * 2 + 0];
        float t2 = weights[tid * 2 + 1];
        if (l == 0) t1 += fabsf(states[(size_t)b * NSTATE + w]);
        float s, c, sz, cz;
        sincosf(0.5f * t1, &s, &c);
        sincosf(0.5f * t2, &sz, &cz);
        gc4[tid] = make_float4(c * cz, -c * sz, -s * sz, -s * cz);
    }
    // |0...0>
    for (unsigned i = tid; i < NSTATE; i += TPB)
        psi[i] = make_float2(i == 0 ? 1.0f : 0.0f, 0.0f);
    __syncthreads();

    for (int l = 0; l < NL; ++l) {
        pass4gates<0>(psi, gc4, l, tid);  __syncthreads();  // wires 13..10
        pass4gates<4>(psi, gc4, l, tid);  __syncthreads();  // wires 9..6
        pass4gates<8>(psi, gc4, l, tid);  __syncthreads();  // wires 5..2
        pass_last    (psi, gc4, l, tid);  __syncthreads();  // wires 1,0 + ring
    }

    // out[b] = sum |amp|^2 * cv(idx) + head_b ; cv = sum_i hw[i]*(1-2*bit)
    float hw[NW];
#pragma unroll
    for (int i = 0; i < NW; ++i) hw[i] = head_w[i];

    const unsigned s = tid & 15u;
    // cvbase for index bits 4..13 (= bits 0..9 of tid); bit j <-> wire 13-j
    float cvbase = 0.0f;
#pragma unroll
    for (int i = 0; i < NW; ++i) cvbase += hw[i];
#pragma unroll
    for (int j = 4; j < 14; ++j)
        if ((tid >> (j - 4)) & 1u) cvbase -= 2.0f * hw[13 - j];

    float acc = 0.0f;
#pragma unroll
    for (int k = 0; k < 16; ++k) {
        const unsigned u = (unsigned)(k ^ (int)s) & 15u;   // index bits 0..3
        const float2 a = psi[u | (tid << 4)];
        const float p = a.x * a.x + a.y * a.y;
        float cv = cvbase;
        if (u & 1u) cv -= 2.0f * hw[13];
        if (u & 2u) cv -= 2.0f * hw[12];
        if (u & 4u) cv -= 2.0f * hw[11];
        if (u & 8u) cv -= 2.0f * hw[10];
        acc += p * cv;
    }
#pragma unroll
    for (int off = 32; off > 0; off >>= 1)
        acc += __shfl_down(acc, off, 64);
    if ((tid & 63u) == 0) wsum[tid >> 6] = acc;
    __syncthreads();
    if (tid == 0) {
        float tot = 0.0f;
#pragma unroll
        for (int i = 0; i < TPB / 64; ++i) tot += wsum[i];
        out[b] = tot + head_b[0];
    }
}

extern "C" void kernel_launch(void* const* d_in, const int* in_sizes, int n_in,
                              void* d_out, int out_size, void* d_ws, size_t ws_size,
                              hipStream_t stream) {
    const float* states  = (const float*)d_in[0];  // (128, 16384)
    const float* weights = (const float*)d_in[1];  // (4, 14, 2)
    const float* head_w  = (const float*)d_in[2];  // (1, 14)
    const float* head_b  = (const float*)d_in[3];  // (1,)
    float* out = (float*)d_out;                    // (128,)
    qsim_kernel<<<BATCH, TPB, NSTATE * sizeof(float2), stream>>>(
        states, weights, head_w, head_b, out);
}